// Round 3
// baseline (223.971 us; speedup 1.0000x reference)
//
#include <hip/hip_runtime.h>

#define L_LEN 131072
#define H_DIM 128
#define P_DIM 128
#define CHUNK 128
#define NCHUNK (L_LEN / CHUNK)   // 1024
#define BT 16

typedef unsigned int uint32;
typedef unsigned short u16;
typedef short bf16x8 __attribute__((ext_vector_type(8)));
typedef float f32x4 __attribute__((ext_vector_type(4)));

// ---- workspace layout (float offsets) ----
constexpr size_t OFF_H   = 0;                                   // h buffer, L x 256 f32
constexpr size_t N_H     = (size_t)L_LEN * P_DIM * 2;           // 33,554,432
constexpr size_t OFF_DA  = OFF_H + N_H;
constexpr size_t OFF_SC  = OFF_DA + 2 * P_DIM;
constexpr size_t OFF_POW = OFF_SC + 2 * P_DIM;
constexpr size_t N_POW   = (size_t)(CHUNK + 1) * P_DIM * 2;     // 33,024
constexpr size_t OFF_E   = OFF_POW + N_POW;                     // NCHUNK x 128 cplx
constexpr size_t OFF_HIN = OFF_E + (size_t)NCHUNK * P_DIM * 2;
constexpr size_t OFF_W1H = OFF_HIN + (size_t)NCHUNK * P_DIM * 2;
constexpr size_t OFF_W1L = OFF_W1H + 16384;
constexpr size_t OFF_W2H = OFF_W1L + 16384;
constexpr size_t OFF_W2L = OFF_W2H + 16384;
// total ≈ 136.7 MB

__device__ __forceinline__ u16 f2bf(float v) {
    uint32 u = __builtin_bit_cast(uint32, v);
    uint32 r = u + 0x7FFFu + ((u >> 16) & 1u);
    return (u16)(r >> 16);
}
__device__ __forceinline__ float bf2f(u16 h) {
    uint32 u = ((uint32)h) << 16;
    return __builtin_bit_cast(float, u);
}
__device__ __forceinline__ float2 cfma(float2 a, float2 h, float2 c) {
    float2 r;
    r.x = fmaf(a.x, h.x, fmaf(-a.y, h.y, c.x));
    r.y = fmaf(a.x, h.y, fmaf(a.y, h.x, c.y));
    return r;
}

// ---- k0a: per-mode scalars + dA power table (powers 0..CHUNK) ----
__global__ void k0a(const float* __restrict__ Arl, const float* __restrict__ Ai,
                    const float* __restrict__ invdt,
                    float* __restrict__ dA, float* __restrict__ sc,
                    float* __restrict__ dApow) {
    int p = threadIdx.x;
    if (p >= P_DIM) return;
    float idt = invdt[p];
    float dt = (idt > 20.f) ? idt : log1pf(expf(idt));   // softplus
    float ar = Arl[p], ai = Ai[p];
    float zr = 0.5f * dt * ar, zi = 0.5f * dt * ai;
    float dr = 1.f - zr, di = -zi;
    float inv = 1.f / (dr * dr + di * di);
    float blr = dr * inv, bli = -di * inv;
    float nr = 1.f + zr, ni = zi;
    float dar = fmaf(blr, nr, -bli * ni);
    float dai = fmaf(blr, ni,  bli * nr);
    dA[2 * p] = dar; dA[2 * p + 1] = dai;
    sc[2 * p] = blr * dt; sc[2 * p + 1] = bli * dt;
    float pr = 1.f, pi = 0.f;
    dApow[p * 2] = pr; dApow[p * 2 + 1] = pi;
    for (int k = 1; k <= CHUNK; ++k) {
        float npr = fmaf(pr, dar, -pi * dai);
        float npi = fmaf(pr, dai,  pi * dar);
        pr = npr; pi = npi;
        dApow[((size_t)k * P_DIM + p) * 2]     = pr;
        dApow[((size_t)k * P_DIM + p) * 2 + 1] = pi;
    }
}

// ---- k0b: W1T[q][h] (q=2p+c) split bf16; W2T[h][q] = (Cr, -Ci) split bf16 ----
__global__ void k0b(const float* __restrict__ Bre, const float* __restrict__ Bim,
                    const float* __restrict__ Cre, const float* __restrict__ Cim,
                    const float* __restrict__ sc,
                    u16* __restrict__ W1H, u16* __restrict__ W1L,
                    u16* __restrict__ W2H, u16* __restrict__ W2L) {
    int i = blockIdx.x * 256 + threadIdx.x;      // 0..16383
    int p = i >> 7, h = i & 127;
    float2 s = ((const float2*)sc)[p];
    float br = Bre[i], bi = Bim[i];
    float re = fmaf(s.x, br, -s.y * bi);
    float im = fmaf(s.x, bi,  s.y * br);
    u16 hr = f2bf(re); W1H[(2 * p) * H_DIM + h]     = hr; W1L[(2 * p) * H_DIM + h]     = f2bf(re - bf2f(hr));
    u16 hi = f2bf(im); W1H[(2 * p + 1) * H_DIM + h] = hi; W1L[(2 * p + 1) * H_DIM + h] = f2bf(im - bf2f(hi));
    int h2 = i >> 7, p2 = i & 127;
    float cr = Cre[i], ci = -Cim[i];
    u16 chr = f2bf(cr); W2H[h2 * 256 + 2 * p2]     = chr; W2L[h2 * 256 + 2 * p2]     = f2bf(cr - bf2f(chr));
    u16 chi = f2bf(ci); W2H[h2 * 256 + 2 * p2 + 1] = chi; W2L[h2 * 256 + 2 * p2 + 1] = f2bf(ci - bf2f(chi));
}

// ---- k12: fused input GEMM + chunk-local scan ----
// block = 1 chunk of 128 rows; GEMM Bu(128x256) = X(128x128) @ W1(128x256)
// (split-bf16 MFMA, B direct from global), then parallel in-block scan,
// writes h_local (fp32) + chunk end-state E.
__global__ __launch_bounds__(256) void k12(const float* __restrict__ x,
                                           const u16* __restrict__ W1H,
                                           const u16* __restrict__ W1L,
                                           const float* __restrict__ dA,
                                           const float* __restrict__ dApow,
                                           float* __restrict__ hout,
                                           float* __restrict__ E) {
    __shared__ __align__(16) char smem[35840];
    u16*   As_hi = (u16*)smem;                 // [128][40]
    u16*   As_lo = (u16*)(smem + 10240);       // [128][40]
    float* SB    = (float*)smem;               // [128][66]  (after GEMM)
    float2* ES   = (float2*)(smem + 33792);    // [8][32]

    int t = threadIdx.x, lane = t & 63, wid = t >> 6;
    int wr = wid >> 1, wc = wid & 1;           // wave covers 64 rows x 128 cols
    size_t l0 = (size_t)blockIdx.x * 128;

    f32x4 acc[4][8];
    #pragma unroll
    for (int a = 0; a < 4; ++a)
        #pragma unroll
        for (int b = 0; b < 8; ++b) acc[a][b] = (f32x4)0.f;

    int ar = lane & 15, ak = (lane >> 4) * 8;

    #pragma unroll
    for (int kt = 0; kt < 4; ++kt) {
        __syncthreads();
        // stage A: 128 rows x 32 k fp32 -> split bf16 in LDS
        #pragma unroll
        for (int j = 0; j < 4; ++j) {
            int f = j * 256 + t; int row = f >> 3, c4 = f & 7;
            float4 v = *(const float4*)(x + (l0 + row) * H_DIM + kt * 32 + c4 * 4);
            ushort4 h4, l4;
            h4.x = f2bf(v.x); l4.x = f2bf(v.x - bf2f(h4.x));
            h4.y = f2bf(v.y); l4.y = f2bf(v.y - bf2f(h4.y));
            h4.z = f2bf(v.z); l4.z = f2bf(v.z - bf2f(h4.z));
            h4.w = f2bf(v.w); l4.w = f2bf(v.w - bf2f(h4.w));
            *(ushort4*)&As_hi[row * 40 + c4 * 4] = h4;
            *(ushort4*)&As_lo[row * 40 + c4 * 4] = l4;
        }
        __syncthreads();
        bf16x8 a_hi[4], a_lo[4];
        #pragma unroll
        for (int mf = 0; mf < 4; ++mf) {
            a_hi[mf] = *(const bf16x8*)&As_hi[(wr * 64 + mf * 16 + ar) * 40 + ak];
            a_lo[mf] = *(const bf16x8*)&As_lo[(wr * 64 + mf * 16 + ar) * 40 + ak];
        }
        #pragma unroll
        for (int nf = 0; nf < 8; ++nf) {
            size_t boff = (size_t)(wc * 128 + nf * 16 + ar) * H_DIM + kt * 32 + ak;
            bf16x8 b_hi = *(const bf16x8*)(W1H + boff);
            bf16x8 b_lo = *(const bf16x8*)(W1L + boff);
            #pragma unroll
            for (int mf = 0; mf < 4; ++mf) {
                acc[mf][nf] = __builtin_amdgcn_mfma_f32_16x16x32_bf16(a_hi[mf], b_hi, acc[mf][nf], 0, 0, 0);
                acc[mf][nf] = __builtin_amdgcn_mfma_f32_16x16x32_bf16(a_lo[mf], b_hi, acc[mf][nf], 0, 0, 0);
                acc[mf][nf] = __builtin_amdgcn_mfma_f32_16x16x32_bf16(a_hi[mf], b_lo, acc[mf][nf], 0, 0, 0);
            }
        }
    }

    // ---- in-block scan over 128 rows, 4 col-quarters (64 cols = 32 modes each) ----
    int p = t & 31, s = t >> 5;                // mode-in-quarter, segment (16 rows)
    int lg4 = lane >> 4;
    #pragma unroll
    for (int qt = 0; qt < 4; ++qt) {
        __syncthreads();
        if (wc == (qt >> 1)) {
            int nb = (qt & 1) * 4;
            #pragma unroll
            for (int mf = 0; mf < 4; ++mf)
                #pragma unroll
                for (int nfl = 0; nfl < 4; ++nfl)
                    #pragma unroll
                    for (int r = 0; r < 4; ++r)
                        SB[(wr * 64 + mf * 16 + lg4 * 4 + r) * 66 + nfl * 16 + ar]
                            = acc[mf][nb + nfl][r];
        }
        __syncthreads();
        int pg = qt * 32 + p;
        float2 a = ((const float2*)dA)[pg];
        float2 loc[16];
        float2 h = make_float2(0.f, 0.f);
        #pragma unroll
        for (int i = 0; i < 16; ++i) {
            float2 bu = *(float2*)&SB[(s * 16 + i) * 66 + 2 * p];
            h = cfma(a, h, bu);
            loc[i] = h;
        }
        ES[s * 32 + p] = h;
        __syncthreads();
        float2 inc = make_float2(0.f, 0.f);
        float2 a16 = ((const float2*)dApow)[16 * P_DIM + pg];
        for (int j = 0; j < s; ++j) inc = cfma(a16, inc, ES[j * 32 + p]);
        #pragma unroll
        for (int i = 0; i < 16; ++i) {
            float2 ap = ((const float2*)dApow)[(size_t)(i + 1) * P_DIM + pg];
            float2 hf = cfma(ap, inc, loc[i]);
            ((float2*)(hout + (l0 + s * 16 + i) * 256))[qt * 32 + p] = hf;
            if (s == 7 && i == 15)
                ((float2*)E)[(size_t)blockIdx.x * P_DIM + pg] = hf;
        }
    }
}

// ---- k3: sequential scan over chunk states (1 block, 128 threads) ----
__global__ void k3(const float* __restrict__ E, const float* __restrict__ dApow,
                   float* __restrict__ Hin) {
    int p = threadIdx.x;
    float2 aS = ((const float2*)dApow)[(size_t)CHUNK * P_DIM + p];
    float2 h = make_float2(0.f, 0.f);
    const float2* e = (const float2*)E;
    float2* hin = (float2*)Hin;
    float2 buf[BT], nbuf[BT];
    #pragma unroll
    for (int i = 0; i < BT; ++i) buf[i] = e[i * P_DIM + p];
    const int NB = NCHUNK / BT;   // 64
    for (int b = 0; b < NB; ++b) {
        if (b + 1 < NB) {
            #pragma unroll
            for (int i = 0; i < BT; ++i) nbuf[i] = e[((b + 1) * BT + i) * P_DIM + p];
        }
        #pragma unroll
        for (int i = 0; i < BT; ++i) {
            hin[(b * BT + i) * P_DIM + p] = h;
            h = cfma(aS, h, buf[i]);
        }
        #pragma unroll
        for (int i = 0; i < BT; ++i) buf[i] = nbuf[i];
    }
}

// ---- k4: y = 2*Re((h_local + dA^k*Hin) @ C^T) + x*D, split-bf16 MFMA ----
__global__ __launch_bounds__(256) void k4(const float* __restrict__ x,
                                          const float* __restrict__ hbuf,
                                          const u16* __restrict__ W2H,
                                          const u16* __restrict__ W2L,
                                          const float* __restrict__ dApow,
                                          const float* __restrict__ Hin,
                                          const float* __restrict__ Dv,
                                          float* __restrict__ y) {
    __shared__ u16 As_hi[128][40], As_lo[128][40];   // 20 KB
    int t = threadIdx.x, lane = t & 63, wid = t >> 6;
    int wr = wid >> 1, wc = wid & 1;                 // 64 rows x 64 cols per wave
    size_t l0 = (size_t)blockIdx.x * 128;
    int g = blockIdx.x;                              // chunk index (CHUNK == BM == 128)
    int pc = t & 15;
    int rg = t >> 4;
    f32x4 acc[4][4];
    #pragma unroll
    for (int a = 0; a < 4; ++a)
        #pragma unroll
        for (int b = 0; b < 4; ++b) acc[a][b] = (f32x4)0.f;

    int ar = lane & 15, ak = (lane >> 4) * 8;

    #pragma unroll
    for (int kt = 0; kt < 8; ++kt) {
        __syncthreads();
        int pglob = kt * 16 + pc;
        float2 hg = ((const float2*)Hin)[(size_t)g * P_DIM + pglob];
        // stage A with fixup: 128 rows x 16 complex
        #pragma unroll
        for (int j = 0; j < 8; ++j) {
            int row = j * 16 + rg;
            size_t lg = l0 + row;
            float2 hl = ((const float2*)hbuf)[lg * P_DIM + pglob];
            int k = (int)(lg & (CHUNK - 1)) + 1;
            float2 ap = ((const float2*)dApow)[(size_t)k * P_DIM + pglob];
            float2 he = cfma(ap, hg, hl);
            u16 hre = f2bf(he.x), lre = f2bf(he.x - bf2f(hre));
            u16 him = f2bf(he.y), lim = f2bf(he.y - bf2f(him));
            ushort2 hv; hv.x = hre; hv.y = him;
            ushort2 lv; lv.x = lre; lv.y = lim;
            *(ushort2*)&As_hi[row][2 * pc] = hv;
            *(ushort2*)&As_lo[row][2 * pc] = lv;
        }
        __syncthreads();
        bf16x8 a_hi[4], a_lo[4];
        #pragma unroll
        for (int mf = 0; mf < 4; ++mf) {
            a_hi[mf] = *(const bf16x8*)&As_hi[wr * 64 + mf * 16 + ar][ak];
            a_lo[mf] = *(const bf16x8*)&As_lo[wr * 64 + mf * 16 + ar][ak];
        }
        #pragma unroll
        for (int nf = 0; nf < 4; ++nf) {
            size_t boff = (size_t)(wc * 64 + nf * 16 + ar) * 256 + kt * 32 + ak;
            bf16x8 b_hi = *(const bf16x8*)(W2H + boff);
            bf16x8 b_lo = *(const bf16x8*)(W2L + boff);
            #pragma unroll
            for (int mf = 0; mf < 4; ++mf) {
                acc[mf][nf] = __builtin_amdgcn_mfma_f32_16x16x32_bf16(a_hi[mf], b_hi, acc[mf][nf], 0, 0, 0);
                acc[mf][nf] = __builtin_amdgcn_mfma_f32_16x16x32_bf16(a_lo[mf], b_hi, acc[mf][nf], 0, 0, 0);
                acc[mf][nf] = __builtin_amdgcn_mfma_f32_16x16x32_bf16(a_hi[mf], b_lo, acc[mf][nf], 0, 0, 0);
            }
        }
    }
    // epilogue: y = 2*acc + x*D
    int sr = (lane >> 4) * 4, scn = lane & 15;
    #pragma unroll
    for (int nf = 0; nf < 4; ++nf) {
        int h = wc * 64 + nf * 16 + scn;
        float d = Dv[h];
        #pragma unroll
        for (int mf = 0; mf < 4; ++mf)
            #pragma unroll
            for (int r = 0; r < 4; ++r) {
                int m = wr * 64 + mf * 16 + sr + r;
                size_t lg = l0 + m;
                y[lg * H_DIM + h] = fmaf(x[lg * H_DIM + h], d, 2.f * acc[mf][nf][r]);
            }
    }
}

extern "C" void kernel_launch(void* const* d_in, const int* in_sizes, int n_in,
                              void* d_out, int out_size, void* d_ws, size_t ws_size,
                              hipStream_t stream) {
    const float* x     = (const float*)d_in[0];
    const float* Arl   = (const float*)d_in[1];
    const float* Ai    = (const float*)d_in[2];
    const float* Bre   = (const float*)d_in[3];
    const float* Bim   = (const float*)d_in[4];
    const float* Cre   = (const float*)d_in[5];
    const float* Cim   = (const float*)d_in[6];
    const float* Dv    = (const float*)d_in[7];
    const float* invdt = (const float*)d_in[8];
    float* y  = (float*)d_out;
    float* ws = (float*)d_ws;

    u16* w1h = (u16*)(ws + OFF_W1H);
    u16* w1l = (u16*)(ws + OFF_W1L);
    u16* w2h = (u16*)(ws + OFF_W2H);
    u16* w2l = (u16*)(ws + OFF_W2L);

    k0a<<<1, 128, 0, stream>>>(Arl, Ai, invdt, ws + OFF_DA, ws + OFF_SC, ws + OFF_POW);
    k0b<<<64, 256, 0, stream>>>(Bre, Bim, Cre, Cim, ws + OFF_SC, w1h, w1l, w2h, w2l);
    k12<<<NCHUNK, 256, 0, stream>>>(x, w1h, w1l, ws + OFF_DA, ws + OFF_POW,
                                    ws + OFF_H, ws + OFF_E);
    k3<<<1, 128, 0, stream>>>(ws + OFF_E, ws + OFF_POW, ws + OFF_HIN);
    k4<<<NCHUNK, 256, 0, stream>>>(x, ws + OFF_H, w2h, w2l, ws + OFF_POW,
                                   ws + OFF_HIN, Dv, y);
}

// Round 4
// 163.236 us; speedup vs baseline: 1.3721x; 1.3721x over previous
//
#include <hip/hip_runtime.h>

#define L_LEN 131072
#define H_DIM 128
#define P_DIM 128
#define CHUNK 128
#define NCHUNK (L_LEN / CHUNK)   // 1024

typedef unsigned int uint32;
typedef unsigned short u16;
typedef short bf16x8 __attribute__((ext_vector_type(8)));
typedef float f32x4 __attribute__((ext_vector_type(4)));

// ---- workspace layout (float offsets) ----
constexpr size_t OFF_BU  = 0;                         // Bu bf16 [L][256] -> 16.8M floats
constexpr size_t N_BUF   = (size_t)L_LEN * 256 / 2;
constexpr size_t OFF_DA  = OFF_BU + N_BUF;
constexpr size_t OFF_SC  = OFF_DA + 256;
constexpr size_t OFF_ET  = OFF_SC + 256;              // E_T [128 modes][1024] cplx
constexpr size_t OFF_HIN = OFF_ET + 2 * 128 * 1024;   // Hin [1024][128] cplx
constexpr size_t OFF_W1H = OFF_HIN + 2 * 1024 * 128;
constexpr size_t OFF_W1L = OFF_W1H + 16384;
constexpr size_t OFF_W2H = OFF_W1L + 16384;
constexpr size_t OFF_W2L = OFF_W2H + 16384;
// total ≈ 70 MB

__device__ __forceinline__ u16 f2bf(float v) {
    uint32 u = __builtin_bit_cast(uint32, v);
    uint32 r = u + 0x7FFFu + ((u >> 16) & 1u);
    return (u16)(r >> 16);
}
__device__ __forceinline__ float bf2f(u16 h) {
    uint32 u = ((uint32)h) << 16;
    return __builtin_bit_cast(float, u);
}
__device__ __forceinline__ float2 cfma(float2 a, float2 h, float2 c) {
    float2 r;
    r.x = fmaf(a.x, h.x, fmaf(-a.y, h.y, c.x));
    r.y = fmaf(a.x, h.y, fmaf(a.y, h.x, c.y));
    return r;
}
__device__ __forceinline__ float2 cmul(float2 a, float2 b) {
    return make_float2(fmaf(a.x, b.x, -a.y * b.y), fmaf(a.x, b.y, a.y * b.x));
}
__device__ __forceinline__ float2 unpk(uint32 w) {
    return make_float2(bf2f((u16)(w & 0xffffu)), bf2f((u16)(w >> 16)));
}
__device__ __forceinline__ uint32 pk(float2 v) {
    return (uint32)f2bf(v.x) | ((uint32)f2bf(v.y) << 16);
}

// ---- k0a: per-mode scalars (dA, sc) ----
__global__ void k0a(const float* __restrict__ Arl, const float* __restrict__ Ai,
                    const float* __restrict__ invdt,
                    float* __restrict__ dA, float* __restrict__ sc) {
    int p = threadIdx.x;
    if (p >= P_DIM) return;
    float idt = invdt[p];
    float dt = (idt > 20.f) ? idt : log1pf(expf(idt));   // softplus
    float ar = Arl[p], ai = Ai[p];
    float zr = 0.5f * dt * ar, zi = 0.5f * dt * ai;
    float dr = 1.f - zr, di = -zi;
    float inv = 1.f / (dr * dr + di * di);
    float blr = dr * inv, bli = -di * inv;
    float nr = 1.f + zr, ni = zi;
    dA[2 * p]     = fmaf(blr, nr, -bli * ni);
    dA[2 * p + 1] = fmaf(blr, ni,  bli * nr);
    sc[2 * p] = blr * dt; sc[2 * p + 1] = bli * dt;
}

// ---- k0b: W1T[q][h] (q=2p+c) split bf16; W2T[h][q] = (Cr, -Ci) split bf16 ----
__global__ void k0b(const float* __restrict__ Bre, const float* __restrict__ Bim,
                    const float* __restrict__ Cre, const float* __restrict__ Cim,
                    const float* __restrict__ sc,
                    u16* __restrict__ W1H, u16* __restrict__ W1L,
                    u16* __restrict__ W2H, u16* __restrict__ W2L) {
    int i = blockIdx.x * 256 + threadIdx.x;      // 0..16383
    int p = i >> 7, h = i & 127;
    float2 s = ((const float2*)sc)[p];
    float br = Bre[i], bi = Bim[i];
    float re = fmaf(s.x, br, -s.y * bi);
    float im = fmaf(s.x, bi,  s.y * br);
    u16 hr = f2bf(re); W1H[(2 * p) * H_DIM + h]     = hr; W1L[(2 * p) * H_DIM + h]     = f2bf(re - bf2f(hr));
    u16 hi = f2bf(im); W1H[(2 * p + 1) * H_DIM + h] = hi; W1L[(2 * p + 1) * H_DIM + h] = f2bf(im - bf2f(hi));
    int h2 = i >> 7, p2 = i & 127;
    float cr = Cre[i], ci = -Cim[i];
    u16 chr = f2bf(cr); W2H[h2 * 256 + 2 * p2]     = chr; W2L[h2 * 256 + 2 * p2]     = f2bf(cr - bf2f(chr));
    u16 chi = f2bf(ci); W2H[h2 * 256 + 2 * p2 + 1] = chi; W2L[h2 * 256 + 2 * p2 + 1] = f2bf(ci - bf2f(chi));
}

// ---- k1: Bu(L x 256) = X(L x 128) @ W1T^T, split-bf16 3-pass MFMA, bf16 out ----
__global__ __launch_bounds__(512, 4) void k1(const float* __restrict__ x,
                                             const u16* __restrict__ W1H,
                                             const u16* __restrict__ W1L,
                                             u16* __restrict__ Bu) {
    __shared__ u16 As_hi[128][40], As_lo[128][40];   // 20 KB
    int t = threadIdx.x, lane = t & 63, wid = t >> 6;  // 8 waves
    int wr = wid >> 2, wc = wid & 3;                   // 2x4: wave = 64 rows x 64 cols
    size_t l0 = (size_t)blockIdx.x * 128;
    f32x4 acc[4][4];
    #pragma unroll
    for (int a = 0; a < 4; ++a)
        #pragma unroll
        for (int b = 0; b < 4; ++b) acc[a][b] = (f32x4)0.f;

    int ar = lane & 15, ak = (lane >> 4) * 8;

    #pragma unroll
    for (int kt = 0; kt < 4; ++kt) {
        __syncthreads();
        // stage A: 128 rows x 32 k fp32 -> split bf16 (1024 float4, 2/thread)
        #pragma unroll
        for (int j = 0; j < 2; ++j) {
            int f = j * 512 + t; int row = f >> 3, c4 = f & 7;
            float4 v = *(const float4*)(x + (l0 + row) * H_DIM + kt * 32 + c4 * 4);
            ushort4 h4, l4;
            h4.x = f2bf(v.x); l4.x = f2bf(v.x - bf2f(h4.x));
            h4.y = f2bf(v.y); l4.y = f2bf(v.y - bf2f(h4.y));
            h4.z = f2bf(v.z); l4.z = f2bf(v.z - bf2f(h4.z));
            h4.w = f2bf(v.w); l4.w = f2bf(v.w - bf2f(h4.w));
            *(ushort4*)&As_hi[row][c4 * 4] = h4;
            *(ushort4*)&As_lo[row][c4 * 4] = l4;
        }
        __syncthreads();
        #pragma unroll
        for (int nf = 0; nf < 4; ++nf) {
            size_t boff = (size_t)(wc * 64 + nf * 16 + ar) * H_DIM + kt * 32 + ak;
            bf16x8 b_hi = *(const bf16x8*)(W1H + boff);
            bf16x8 b_lo = *(const bf16x8*)(W1L + boff);
            #pragma unroll
            for (int mf = 0; mf < 4; ++mf) {
                bf16x8 a_hi = *(const bf16x8*)&As_hi[wr * 64 + mf * 16 + ar][ak];
                bf16x8 a_lo = *(const bf16x8*)&As_lo[wr * 64 + mf * 16 + ar][ak];
                acc[mf][nf] = __builtin_amdgcn_mfma_f32_16x16x32_bf16(a_hi, b_hi, acc[mf][nf], 0, 0, 0);
                acc[mf][nf] = __builtin_amdgcn_mfma_f32_16x16x32_bf16(a_lo, b_hi, acc[mf][nf], 0, 0, 0);
                acc[mf][nf] = __builtin_amdgcn_mfma_f32_16x16x32_bf16(a_hi, b_lo, acc[mf][nf], 0, 0, 0);
            }
        }
    }
    int sr = (lane >> 4) * 4, scn = lane & 15;
    #pragma unroll
    for (int mf = 0; mf < 4; ++mf)
        #pragma unroll
        for (int nf = 0; nf < 4; ++nf)
            #pragma unroll
            for (int r = 0; r < 4; ++r) {
                int row = wr * 64 + mf * 16 + sr + r;
                int col = wc * 64 + nf * 16 + scn;
                Bu[(l0 + row) * 256 + col] = f2bf(acc[mf][nf][r]);
            }
}

// ---- k2: chunk end-states E_T[p][g] via Horner over 128 rows ----
__global__ __launch_bounds__(128) void k2(const u16* __restrict__ Bu,
                                          const float* __restrict__ dA,
                                          float* __restrict__ ET) {
    int p = threadIdx.x;          // mode
    int g = blockIdx.x;           // chunk
    float2 a = ((const float2*)dA)[p];
    const uint32* bu = (const uint32*)(Bu + (size_t)g * 128 * 256) + p;
    float2 e = make_float2(0.f, 0.f);
    uint32 buf[16], nb[16];
    #pragma unroll
    for (int i = 0; i < 16; ++i) buf[i] = bu[i * 128];
    #pragma unroll 1
    for (int b = 0; b < 8; ++b) {
        if (b + 1 < 8) {
            #pragma unroll
            for (int i = 0; i < 16; ++i) nb[i] = bu[((b + 1) * 16 + i) * 128];
        }
        #pragma unroll
        for (int i = 0; i < 16; ++i) e = cfma(a, e, unpk(buf[i]));
        #pragma unroll
        for (int i = 0; i < 16; ++i) buf[i] = nb[i];
    }
    ((float2*)ET)[(size_t)p * NCHUNK + g] = e;
}

// ---- k3: per-mode parallel scan over 1024 chunk states -> Hin[g][p] ----
__global__ __launch_bounds__(256) void k3(const float* __restrict__ ET,
                                          const float* __restrict__ dA,
                                          float* __restrict__ Hin) {
    __shared__ float4 s0[256], s1[256];
    int m = blockIdx.x, j = threadIdx.x;
    float2 aS = ((const float2*)dA)[m];
    #pragma unroll
    for (int i = 0; i < 7; ++i) aS = cmul(aS, aS);     // dA^128
    const float2* e = (const float2*)ET + (size_t)m * NCHUNK + j * 4;
    float2 e0 = e[0], e1 = e[1], e2 = e[2], e3 = e[3];
    float2 B = e0;
    B = cfma(aS, B, e1); B = cfma(aS, B, e2); B = cfma(aS, B, e3);
    float2 A2 = cmul(aS, aS); float2 A = cmul(A2, A2); // aS^4
    s0[j] = make_float4(A.x, A.y, B.x, B.y);
    __syncthreads();
    float4 *src = s0, *dst = s1;
    for (int d = 1; d < 256; d <<= 1) {
        float4 v = src[j];
        if (j >= d) {
            float4 u = src[j - d];
            float2 uA = make_float2(u.x, u.y), uB = make_float2(u.z, u.w);
            float2 vA = make_float2(v.x, v.y), vB = make_float2(v.z, v.w);
            float2 nA = cmul(uA, vA);
            float2 nB = cfma(vA, uB, vB);
            v = make_float4(nA.x, nA.y, nB.x, nB.y);
        }
        dst[j] = v;
        __syncthreads();
        float4* tmp = src; src = dst; dst = tmp;
    }
    float2 pre = make_float2(0.f, 0.f);
    if (j > 0) { float4 u = src[j - 1]; pre = make_float2(u.z, u.w); }
    float2* hin = (float2*)Hin;
    hin[(size_t)(j * 4 + 0) * P_DIM + m] = pre;
    pre = cfma(aS, pre, e0); hin[(size_t)(j * 4 + 1) * P_DIM + m] = pre;
    pre = cfma(aS, pre, e1); hin[(size_t)(j * 4 + 2) * P_DIM + m] = pre;
    pre = cfma(aS, pre, e2); hin[(size_t)(j * 4 + 3) * P_DIM + m] = pre;
}

// ---- k4: stage Bu -> LDS (swizzled), in-place seeded scan, GEMM vs W2, y out ----
__global__ __launch_bounds__(512, 4) void k4(const float* __restrict__ x,
                                             const u16* __restrict__ Bu,
                                             const u16* __restrict__ W2H,
                                             const u16* __restrict__ W2L,
                                             const float* __restrict__ dA,
                                             const float* __restrict__ Hin,
                                             const float* __restrict__ Dv,
                                             float* __restrict__ y) {
    __shared__ u16 SB[128 * 256];    // 64 KB, 16B-block XOR swizzle: blk ^= (row&7)
    int t = threadIdx.x, lane = t & 63, wid = t >> 6;  // 8 waves
    int wr = wid >> 2, wc = wid & 3;                   // 2x4: wave = 64 rows x 32 cols
    int g = blockIdx.x;
    size_t l0 = (size_t)g * 128;

    // stage: 128 rows x 32 x 16B, 8 per thread
    #pragma unroll
    for (int j = 0; j < 8; ++j) {
        int f = j * 512 + t; int row = f >> 5, blk = f & 31;
        uint4 v = *(const uint4*)(Bu + (l0 + row) * 256 + blk * 8);
        *(uint4*)&SB[row * 256 + ((blk ^ (row & 7)) * 8)] = v;
    }
    __syncthreads();

    // seeded in-place scan: thread p owns column (mode) p
    if (t < 128) {
        int p = t;
        float2 a = ((const float2*)dA)[p];
        float2 h = ((const float2*)Hin)[(size_t)g * P_DIM + p];
        int pb = p >> 2, po = (p & 3) * 2;
        uint32 cur[8], nxt[8];
        #pragma unroll
        for (int i = 0; i < 8; ++i)
            cur[i] = *(const uint32*)&SB[i * 256 + ((pb ^ (i & 7)) * 8) + po];
        #pragma unroll 1
        for (int b = 0; b < 16; ++b) {
            if (b < 15) {
                #pragma unroll
                for (int i = 0; i < 8; ++i) {
                    int r = b * 8 + 8 + i;
                    nxt[i] = *(const uint32*)&SB[r * 256 + ((pb ^ (r & 7)) * 8) + po];
                }
            }
            #pragma unroll
            for (int i = 0; i < 8; ++i) {
                int r = b * 8 + i;
                h = cfma(a, h, unpk(cur[i]));
                *(uint32*)&SB[r * 256 + ((pb ^ (r & 7)) * 8) + po] = pk(h);
            }
            #pragma unroll
            for (int i = 0; i < 8; ++i) cur[i] = nxt[i];
        }
    }
    __syncthreads();

    // GEMM: y128x128 = h(128x256) @ W2T^T, A from swizzled LDS, B split 2-pass
    f32x4 acc[4][2];
    #pragma unroll
    for (int a = 0; a < 4; ++a)
        #pragma unroll
        for (int b = 0; b < 2; ++b) acc[a][b] = (f32x4)0.f;
    int ar = lane & 15, akb = lane >> 4;
    #pragma unroll
    for (int kk = 0; kk < 8; ++kk) {
        bf16x8 af[4];
        #pragma unroll
        for (int mf = 0; mf < 4; ++mf) {
            int row = wr * 64 + mf * 16 + ar;
            int blk = kk * 4 + akb;
            af[mf] = *(const bf16x8*)&SB[row * 256 + ((blk ^ (row & 7)) * 8)];
        }
        #pragma unroll
        for (int nf = 0; nf < 2; ++nf) {
            size_t boff = (size_t)(wc * 32 + nf * 16 + ar) * 256 + kk * 32 + akb * 8;
            bf16x8 b_hi = *(const bf16x8*)(W2H + boff);
            bf16x8 b_lo = *(const bf16x8*)(W2L + boff);
            #pragma unroll
            for (int mf = 0; mf < 4; ++mf) {
                acc[mf][nf] = __builtin_amdgcn_mfma_f32_16x16x32_bf16(af[mf], b_hi, acc[mf][nf], 0, 0, 0);
                acc[mf][nf] = __builtin_amdgcn_mfma_f32_16x16x32_bf16(af[mf], b_lo, acc[mf][nf], 0, 0, 0);
            }
        }
    }
    // epilogue: y = 2*acc + x*D
    int sr = (lane >> 4) * 4, scn = lane & 15;
    #pragma unroll
    for (int nf = 0; nf < 2; ++nf) {
        int h = wc * 32 + nf * 16 + scn;
        float d = Dv[h];
        #pragma unroll
        for (int mf = 0; mf < 4; ++mf)
            #pragma unroll
            for (int r = 0; r < 4; ++r) {
                int m = wr * 64 + mf * 16 + sr + r;
                size_t lg = l0 + m;
                y[lg * H_DIM + h] = fmaf(x[lg * H_DIM + h], d, 2.f * acc[mf][nf][r]);
            }
    }
}

extern "C" void kernel_launch(void* const* d_in, const int* in_sizes, int n_in,
                              void* d_out, int out_size, void* d_ws, size_t ws_size,
                              hipStream_t stream) {
    const float* x     = (const float*)d_in[0];
    const float* Arl   = (const float*)d_in[1];
    const float* Ai    = (const float*)d_in[2];
    const float* Bre   = (const float*)d_in[3];
    const float* Bim   = (const float*)d_in[4];
    const float* Cre   = (const float*)d_in[5];
    const float* Cim   = (const float*)d_in[6];
    const float* Dv    = (const float*)d_in[7];
    const float* invdt = (const float*)d_in[8];
    float* y  = (float*)d_out;
    float* ws = (float*)d_ws;

    u16* bu  = (u16*)(ws + OFF_BU);
    u16* w1h = (u16*)(ws + OFF_W1H);
    u16* w1l = (u16*)(ws + OFF_W1L);
    u16* w2h = (u16*)(ws + OFF_W2H);
    u16* w2l = (u16*)(ws + OFF_W2L);

    k0a<<<1, 128, 0, stream>>>(Arl, Ai, invdt, ws + OFF_DA, ws + OFF_SC);
    k0b<<<64, 256, 0, stream>>>(Bre, Bim, Cre, Cim, ws + OFF_SC, w1h, w1l, w2h, w2l);
    k1<<<NCHUNK, 512, 0, stream>>>(x, w1h, w1l, bu);
    k2<<<NCHUNK, 128, 0, stream>>>(bu, ws + OFF_DA, ws + OFF_ET);
    k3<<<128, 256, 0, stream>>>(ws + OFF_ET, ws + OFF_DA, ws + OFF_HIN);
    k4<<<NCHUNK, 512, 0, stream>>>(x, bu, w2h, w2l, ws + OFF_DA,
                                   ws + OFF_HIN, Dv, y);
}

// Round 5
// 160.243 us; speedup vs baseline: 1.3977x; 1.0187x over previous
//
#include <hip/hip_runtime.h>

#define L_LEN 131072
#define H_DIM 128
#define P_DIM 128
#define SEG 32
#define NSEG (L_LEN / SEG)       // 4096
#define ROWS 64
#define NBLK (L_LEN / ROWS)      // 2048

typedef unsigned int uint32;
typedef unsigned short u16;
typedef short bf16x8 __attribute__((ext_vector_type(8)));
typedef float f32x4 __attribute__((ext_vector_type(4)));

// ---- workspace layout (float offsets) ----
constexpr size_t OFF_BU  = 0;                          // Bu bf16 [L][256]
constexpr size_t N_BUF   = (size_t)L_LEN * 256 / 2;    // 16,777,216 floats
constexpr size_t OFF_DA  = OFF_BU + N_BUF;
constexpr size_t OFF_SC  = OFF_DA + 256;
constexpr size_t OFF_E   = OFF_SC + 256;               // E [NSEG][128] cplx
constexpr size_t OFF_HIN = OFF_E + (size_t)NSEG * 256; // Hin [NSEG][128] cplx
constexpr size_t OFF_W1H = OFF_HIN + (size_t)NSEG * 256;
constexpr size_t OFF_W1L = OFF_W1H + 16384;
constexpr size_t OFF_W2H = OFF_W1L + 16384;
constexpr size_t OFF_W2L = OFF_W2H + 16384;
// total ≈ 76 MB

__device__ __forceinline__ u16 f2bf(float v) {
    uint32 u = __builtin_bit_cast(uint32, v);
    uint32 r = u + 0x7FFFu + ((u >> 16) & 1u);
    return (u16)(r >> 16);
}
__device__ __forceinline__ float bf2f(u16 h) {
    uint32 u = ((uint32)h) << 16;
    return __builtin_bit_cast(float, u);
}
__device__ __forceinline__ float2 cfma(float2 a, float2 h, float2 c) {
    float2 r;
    r.x = fmaf(a.x, h.x, fmaf(-a.y, h.y, c.x));
    r.y = fmaf(a.x, h.y, fmaf(a.y, h.x, c.y));
    return r;
}
__device__ __forceinline__ float2 cmul(float2 a, float2 b) {
    return make_float2(fmaf(a.x, b.x, -a.y * b.y), fmaf(a.x, b.y, a.y * b.x));
}
__device__ __forceinline__ float2 unpk(uint32 w) {
    return make_float2(bf2f((u16)(w & 0xffffu)), bf2f((u16)(w >> 16)));
}
__device__ __forceinline__ uint32 pk(float2 v) {
    return (uint32)f2bf(v.x) | ((uint32)f2bf(v.y) << 16);
}

// ---- k0a: per-mode scalars (dA, sc) ----
__global__ void k0a(const float* __restrict__ Arl, const float* __restrict__ Ai,
                    const float* __restrict__ invdt,
                    float* __restrict__ dA, float* __restrict__ sc) {
    int p = threadIdx.x;
    if (p >= P_DIM) return;
    float idt = invdt[p];
    float dt = (idt > 20.f) ? idt : log1pf(expf(idt));   // softplus
    float ar = Arl[p], ai = Ai[p];
    float zr = 0.5f * dt * ar, zi = 0.5f * dt * ai;
    float dr = 1.f - zr, di = -zi;
    float inv = 1.f / (dr * dr + di * di);
    float blr = dr * inv, bli = -di * inv;
    float nr = 1.f + zr, ni = zi;
    dA[2 * p]     = fmaf(blr, nr, -bli * ni);
    dA[2 * p + 1] = fmaf(blr, ni,  bli * nr);
    sc[2 * p] = blr * dt; sc[2 * p + 1] = bli * dt;
}

// ---- k0b: W1T[q][h] (q=2p+c) split bf16; W2T[h][q] = 2*(Cr, -Ci) split bf16 ----
__global__ void k0b(const float* __restrict__ Bre, const float* __restrict__ Bim,
                    const float* __restrict__ Cre, const float* __restrict__ Cim,
                    const float* __restrict__ sc,
                    u16* __restrict__ W1H, u16* __restrict__ W1L,
                    u16* __restrict__ W2H, u16* __restrict__ W2L) {
    int i = blockIdx.x * 256 + threadIdx.x;      // 0..16383
    int p = i >> 7, h = i & 127;
    float2 s = ((const float2*)sc)[p];
    float br = Bre[i], bi = Bim[i];
    float re = fmaf(s.x, br, -s.y * bi);
    float im = fmaf(s.x, bi,  s.y * br);
    u16 hr = f2bf(re); W1H[(2 * p) * H_DIM + h]     = hr; W1L[(2 * p) * H_DIM + h]     = f2bf(re - bf2f(hr));
    u16 hi = f2bf(im); W1H[(2 * p + 1) * H_DIM + h] = hi; W1L[(2 * p + 1) * H_DIM + h] = f2bf(im - bf2f(hi));
    int h2 = i >> 7, p2 = i & 127;
    float cr = 2.f * Cre[i], ci = -2.f * Cim[i];   // CONJ_SYM 2x folded in
    u16 chr = f2bf(cr); W2H[h2 * 256 + 2 * p2]     = chr; W2L[h2 * 256 + 2 * p2]     = f2bf(cr - bf2f(chr));
    u16 chi = f2bf(ci); W2H[h2 * 256 + 2 * p2 + 1] = chi; W2L[h2 * 256 + 2 * p2 + 1] = f2bf(ci - bf2f(chi));
}

// ---- k1: Bu = X @ W1 (split-bf16 3-pass MFMA) + seg end-states E, coalesced Bu out ----
__global__ __launch_bounds__(256, 3) void k1(const float* __restrict__ x,
                                             const u16* __restrict__ W1H,
                                             const u16* __restrict__ W1L,
                                             const float* __restrict__ dA,
                                             u16* __restrict__ Bu,
                                             float* __restrict__ E) {
    __shared__ __align__(16) char smem[32768];
    u16* As_hi = (u16*)smem;              // [64][40] during GEMM
    u16* As_lo = (u16*)(smem + 5120);
    u16* SB    = (u16*)smem;              // [64][256] swizzled, after GEMM
    int t = threadIdx.x, lane = t & 63, wid = t >> 6;   // 4 waves, each 64 rows x 64 cols
    size_t l0 = (size_t)blockIdx.x * ROWS;
    f32x4 acc[4][4];
    #pragma unroll
    for (int a = 0; a < 4; ++a)
        #pragma unroll
        for (int b = 0; b < 4; ++b) acc[a][b] = (f32x4)0.f;
    int ar = lane & 15, ak = (lane >> 4) * 8;

    #pragma unroll
    for (int kt = 0; kt < 4; ++kt) {
        __syncthreads();
        // stage A: 64 rows x 32 k fp32 -> split bf16 (512 float4, 2/thread)
        #pragma unroll
        for (int j = 0; j < 2; ++j) {
            int f = j * 256 + t; int row = f >> 3, c4 = f & 7;
            float4 v = *(const float4*)(x + (l0 + row) * H_DIM + kt * 32 + c4 * 4);
            ushort4 h4, l4;
            h4.x = f2bf(v.x); l4.x = f2bf(v.x - bf2f(h4.x));
            h4.y = f2bf(v.y); l4.y = f2bf(v.y - bf2f(h4.y));
            h4.z = f2bf(v.z); l4.z = f2bf(v.z - bf2f(h4.z));
            h4.w = f2bf(v.w); l4.w = f2bf(v.w - bf2f(h4.w));
            *(ushort4*)&As_hi[row * 40 + c4 * 4] = h4;
            *(ushort4*)&As_lo[row * 40 + c4 * 4] = l4;
        }
        __syncthreads();
        bf16x8 a_hi[4], a_lo[4];
        #pragma unroll
        for (int mf = 0; mf < 4; ++mf) {
            a_hi[mf] = *(const bf16x8*)&As_hi[(mf * 16 + ar) * 40 + ak];
            a_lo[mf] = *(const bf16x8*)&As_lo[(mf * 16 + ar) * 40 + ak];
        }
        #pragma unroll
        for (int nf = 0; nf < 4; ++nf) {
            size_t boff = (size_t)(wid * 64 + nf * 16 + ar) * H_DIM + kt * 32 + ak;
            bf16x8 b_hi = *(const bf16x8*)(W1H + boff);
            bf16x8 b_lo = *(const bf16x8*)(W1L + boff);
            #pragma unroll
            for (int mf = 0; mf < 4; ++mf) {
                acc[mf][nf] = __builtin_amdgcn_mfma_f32_16x16x32_bf16(a_hi[mf], b_hi, acc[mf][nf], 0, 0, 0);
                acc[mf][nf] = __builtin_amdgcn_mfma_f32_16x16x32_bf16(a_lo[mf], b_hi, acc[mf][nf], 0, 0, 0);
                acc[mf][nf] = __builtin_amdgcn_mfma_f32_16x16x32_bf16(a_hi[mf], b_lo, acc[mf][nf], 0, 0, 0);
            }
        }
    }
    __syncthreads();
    // acc -> SB bf16, 16B-block XOR swizzle (blk ^= row&7)
    int sr = (lane >> 4) * 4, scn = lane & 15;
    #pragma unroll
    for (int mf = 0; mf < 4; ++mf)
        #pragma unroll
        for (int nf = 0; nf < 4; ++nf)
            #pragma unroll
            for (int r = 0; r < 4; ++r) {
                int row = mf * 16 + sr + r;
                int col = wid * 64 + nf * 16 + scn;
                SB[row * 256 + (((col >> 3) ^ (row & 7)) << 3) + (col & 7)]
                    = f2bf(acc[mf][nf][r]);
            }
    __syncthreads();
    // seg end-state scan (2 segs x 128 modes, all 256 threads)
    {
        int s = t >> 7, p = t & 127;
        float2 a = ((const float2*)dA)[p];
        float2 e = make_float2(0.f, 0.f);
        #pragma unroll
        for (int i = 0; i < SEG; ++i) {
            int row = s * 32 + i;
            uint32 w = *(const uint32*)&SB[row * 256 + (((p >> 2) ^ (row & 7)) << 3) + (p & 3) * 2];
            e = cfma(a, e, unpk(w));
        }
        ((float2*)E)[((size_t)blockIdx.x * 2 + s) * P_DIM + p] = e;
    }
    // Bu store, fully coalesced (un-swizzle read, linear write)
    #pragma unroll
    for (int j = 0; j < 8; ++j) {
        int f = j * 256 + t; int row = f >> 5, blk = f & 31;
        uint4 v = *(const uint4*)&SB[row * 256 + ((blk ^ (row & 7)) << 3)];
        *(uint4*)(Bu + (l0 + row) * 256 + blk * 8) = v;
    }
}

// ---- k3: per-mode parallel scan over 4096 seg states -> Hin[seg][p] ----
__global__ __launch_bounds__(256) void k3(const float* __restrict__ E,
                                          const float* __restrict__ dA,
                                          float* __restrict__ Hin) {
    __shared__ float4 s0[256], s1[256];
    int m = blockIdx.x, j = threadIdx.x;
    float2 aS = ((const float2*)dA)[m];
    #pragma unroll
    for (int i = 0; i < 5; ++i) aS = cmul(aS, aS);     // dA^32
    const float2* e = (const float2*)E;
    float2 ebuf[16];
    #pragma unroll
    for (int i = 0; i < 16; ++i) ebuf[i] = e[(size_t)(j * 16 + i) * P_DIM + m];
    float2 B = ebuf[0];
    #pragma unroll
    for (int i = 1; i < 16; ++i) B = cfma(aS, B, ebuf[i]);
    float2 A = aS;
    #pragma unroll
    for (int i = 0; i < 4; ++i) A = cmul(A, A);        // aS^16
    s0[j] = make_float4(A.x, A.y, B.x, B.y);
    __syncthreads();
    float4 *src = s0, *dst = s1;
    for (int d = 1; d < 256; d <<= 1) {
        float4 v = src[j];
        if (j >= d) {
            float4 u = src[j - d];
            float2 uA = make_float2(u.x, u.y), uB = make_float2(u.z, u.w);
            float2 vA = make_float2(v.x, v.y), vB = make_float2(v.z, v.w);
            float2 nA = cmul(uA, vA);
            float2 nB = cfma(vA, uB, vB);
            v = make_float4(nA.x, nA.y, nB.x, nB.y);
        }
        dst[j] = v;
        __syncthreads();
        float4* tmp = src; src = dst; dst = tmp;
    }
    float2 pre = make_float2(0.f, 0.f);
    if (j > 0) { float4 u = src[j - 1]; pre = make_float2(u.z, u.w); }
    float2* hin = (float2*)Hin;
    #pragma unroll
    for (int i = 0; i < 16; ++i) {
        hin[(size_t)(j * 16 + i) * P_DIM + m] = pre;
        pre = cfma(aS, pre, ebuf[i]);
    }
}

// ---- k4: stage Bu, seeded 32-step scan (all threads), GEMM vs W2, LDS-coalesced y ----
__global__ __launch_bounds__(256, 4) void k4(const float* __restrict__ x,
                                             const u16* __restrict__ Bu,
                                             const u16* __restrict__ W2H,
                                             const u16* __restrict__ W2L,
                                             const float* __restrict__ dA,
                                             const float* __restrict__ Hin,
                                             const float* __restrict__ Dv,
                                             float* __restrict__ y) {
    __shared__ __align__(16) char smem[33280];
    u16*   SB  = (u16*)smem;       // [64][256] swizzled bf16
    float* SBF = (float*)smem;     // [64][130] f32 y-tile (after GEMM)
    int t = threadIdx.x, lane = t & 63, wid = t >> 6;
    int wr = wid >> 1, wc = wid & 1;                   // wave = 32 rows x 64 cols
    size_t l0 = (size_t)blockIdx.x * ROWS;

    // stage Bu -> LDS swizzled (2048 uint4, 8/thread, coalesced)
    #pragma unroll
    for (int j = 0; j < 8; ++j) {
        int f = j * 256 + t; int row = f >> 5, blk = f & 31;
        uint4 v = *(const uint4*)(Bu + (l0 + row) * 256 + blk * 8);
        *(uint4*)&SB[row * 256 + ((blk ^ (row & 7)) << 3)] = v;
    }
    __syncthreads();

    // seeded scan: 2 segs x 128 modes, 32 steps, in-place bf16
    {
        int s = t >> 7, p = t & 127;
        float2 a = ((const float2*)dA)[p];
        float2 h = ((const float2*)Hin)[((size_t)blockIdx.x * 2 + s) * P_DIM + p];
        #pragma unroll
        for (int i = 0; i < SEG; ++i) {
            int row = s * 32 + i;
            uint32* w = (uint32*)&SB[row * 256 + (((p >> 2) ^ (row & 7)) << 3) + (p & 3) * 2];
            h = cfma(a, h, unpk(*w));
            *w = pk(h);
        }
    }
    __syncthreads();

    // GEMM: y(64x128) = h(64x256) @ W2T^T, split-bf16 2-pass
    f32x4 acc[2][4];
    #pragma unroll
    for (int a = 0; a < 2; ++a)
        #pragma unroll
        for (int b = 0; b < 4; ++b) acc[a][b] = (f32x4)0.f;
    int ar = lane & 15, akb = lane >> 4;
    #pragma unroll
    for (int kk = 0; kk < 8; ++kk) {
        bf16x8 af[2];
        #pragma unroll
        for (int mf = 0; mf < 2; ++mf) {
            int row = wr * 32 + mf * 16 + ar;
            int blk = kk * 4 + akb;
            af[mf] = *(const bf16x8*)&SB[row * 256 + ((blk ^ (row & 7)) << 3)];
        }
        #pragma unroll
        for (int nf = 0; nf < 4; ++nf) {
            size_t boff = (size_t)(wc * 64 + nf * 16 + ar) * 256 + kk * 32 + akb * 8;
            bf16x8 b_hi = *(const bf16x8*)(W2H + boff);
            bf16x8 b_lo = *(const bf16x8*)(W2L + boff);
            #pragma unroll
            for (int mf = 0; mf < 2; ++mf) {
                acc[mf][nf] = __builtin_amdgcn_mfma_f32_16x16x32_bf16(af[mf], b_hi, acc[mf][nf], 0, 0, 0);
                acc[mf][nf] = __builtin_amdgcn_mfma_f32_16x16x32_bf16(af[mf], b_lo, acc[mf][nf], 0, 0, 0);
            }
        }
    }
    __syncthreads();
    // acc -> SBF[64][130] (pad 130: conflict-free row groups)
    int sr = (lane >> 4) * 4, scn = lane & 15;
    #pragma unroll
    for (int mf = 0; mf < 2; ++mf)
        #pragma unroll
        for (int nf = 0; nf < 4; ++nf)
            #pragma unroll
            for (int r = 0; r < 4; ++r) {
                int row = wr * 32 + mf * 16 + sr + r;
                int col = wc * 64 + nf * 16 + scn;
                SBF[row * 130 + col] = acc[mf][nf][r];
            }
    __syncthreads();
    // y write: fully coalesced float4 rows, fused x*D (2x already in W2)
    int c4 = t & 31;
    float4 dv = *(const float4*)(Dv + c4 * 4);
    #pragma unroll
    for (int j = 0; j < 8; ++j) {
        int row = j * 8 + (t >> 5);
        float4 sv = *(float4*)&SBF[row * 130 + c4 * 4];
        float4 xv = *(const float4*)(x + (l0 + row) * H_DIM + c4 * 4);
        float4 out;
        out.x = fmaf(xv.x, dv.x, sv.x);
        out.y = fmaf(xv.y, dv.y, sv.y);
        out.z = fmaf(xv.z, dv.z, sv.z);
        out.w = fmaf(xv.w, dv.w, sv.w);
        *(float4*)(y + (l0 + row) * H_DIM + c4 * 4) = out;
    }
}

extern "C" void kernel_launch(void* const* d_in, const int* in_sizes, int n_in,
                              void* d_out, int out_size, void* d_ws, size_t ws_size,
                              hipStream_t stream) {
    const float* x     = (const float*)d_in[0];
    const float* Arl   = (const float*)d_in[1];
    const float* Ai    = (const float*)d_in[2];
    const float* Bre   = (const float*)d_in[3];
    const float* Bim   = (const float*)d_in[4];
    const float* Cre   = (const float*)d_in[5];
    const float* Cim   = (const float*)d_in[6];
    const float* Dv    = (const float*)d_in[7];
    const float* invdt = (const float*)d_in[8];
    float* y  = (float*)d_out;
    float* ws = (float*)d_ws;

    u16* bu  = (u16*)(ws + OFF_BU);
    u16* w1h = (u16*)(ws + OFF_W1H);
    u16* w1l = (u16*)(ws + OFF_W1L);
    u16* w2h = (u16*)(ws + OFF_W2H);
    u16* w2l = (u16*)(ws + OFF_W2L);

    k0a<<<1, 128, 0, stream>>>(Arl, Ai, invdt, ws + OFF_DA, ws + OFF_SC);
    k0b<<<64, 256, 0, stream>>>(Bre, Bim, Cre, Cim, ws + OFF_SC, w1h, w1l, w2h, w2l);
    k1<<<NBLK, 256, 0, stream>>>(x, w1h, w1l, ws + OFF_DA, bu, ws + OFF_E);
    k3<<<128, 256, 0, stream>>>(ws + OFF_E, ws + OFF_DA, ws + OFF_HIN);
    k4<<<NBLK, 256, 0, stream>>>(x, bu, w2h, w2l, ws + OFF_DA,
                                 ws + OFF_HIN, Dv, y);
}

// Round 6
// 159.105 us; speedup vs baseline: 1.4077x; 1.0072x over previous
//
#include <hip/hip_runtime.h>

#define L_LEN 131072
#define H_DIM 128
#define P_DIM 128
#define SEG 32
#define NSEG (L_LEN / SEG)       // 4096
#define ROWS 64
#define NBLK (L_LEN / ROWS)      // 2048

typedef unsigned int uint32;
typedef unsigned short u16;
typedef short bf16x8 __attribute__((ext_vector_type(8)));
typedef float f32x4 __attribute__((ext_vector_type(4)));

// ---- workspace layout (float offsets) ----
constexpr size_t OFF_HL  = 0;                          // h_loc bf16 [L][256]
constexpr size_t N_HLF   = (size_t)L_LEN * 256 / 2;    // 16,777,216 floats
constexpr size_t OFF_DA  = OFF_HL + N_HLF;
constexpr size_t OFF_SC  = OFF_DA + 256;
constexpr size_t OFF_POW = OFF_SC + 256;               // dA^{i+1}, i=0..31: [32][128] cplx
constexpr size_t OFF_E   = OFF_POW + 32 * 256;         // E [NSEG][128] cplx
constexpr size_t OFF_HIN = OFF_E + (size_t)NSEG * 256; // Hin [NSEG][128] cplx
constexpr size_t OFF_W1H = OFF_HIN + (size_t)NSEG * 256;
constexpr size_t OFF_W1L = OFF_W1H + 16384;
constexpr size_t OFF_W2H = OFF_W1L + 16384;
constexpr size_t OFF_W2L = OFF_W2H + 16384;
// total ≈ 76 MB

__device__ __forceinline__ u16 f2bf(float v) {
    uint32 u = __builtin_bit_cast(uint32, v);
    uint32 r = u + 0x7FFFu + ((u >> 16) & 1u);
    return (u16)(r >> 16);
}
__device__ __forceinline__ float bf2f(u16 h) {
    uint32 u = ((uint32)h) << 16;
    return __builtin_bit_cast(float, u);
}
__device__ __forceinline__ float2 cfma(float2 a, float2 h, float2 c) {
    float2 r;
    r.x = fmaf(a.x, h.x, fmaf(-a.y, h.y, c.x));
    r.y = fmaf(a.x, h.y, fmaf(a.y, h.x, c.y));
    return r;
}
__device__ __forceinline__ float2 cmul(float2 a, float2 b) {
    return make_float2(fmaf(a.x, b.x, -a.y * b.y), fmaf(a.x, b.y, a.y * b.x));
}
__device__ __forceinline__ float2 unpk(uint32 w) {
    return make_float2(bf2f((u16)(w & 0xffffu)), bf2f((u16)(w >> 16)));
}
__device__ __forceinline__ uint32 pk(float2 v) {
    return (uint32)f2bf(v.x) | ((uint32)f2bf(v.y) << 16);
}

// ---- k0a: per-mode scalars (dA, sc) + dA power table dA^{i+1}, i=0..31 ----
__global__ void k0a(const float* __restrict__ Arl, const float* __restrict__ Ai,
                    const float* __restrict__ invdt,
                    float* __restrict__ dA, float* __restrict__ sc,
                    float* __restrict__ dApow) {
    int p = threadIdx.x;
    if (p >= P_DIM) return;
    float idt = invdt[p];
    float dt = (idt > 20.f) ? idt : log1pf(expf(idt));   // softplus
    float ar = Arl[p], ai = Ai[p];
    float zr = 0.5f * dt * ar, zi = 0.5f * dt * ai;
    float dr = 1.f - zr, di = -zi;
    float inv = 1.f / (dr * dr + di * di);
    float blr = dr * inv, bli = -di * inv;
    float nr = 1.f + zr, ni = zi;
    float2 a = make_float2(fmaf(blr, nr, -bli * ni), fmaf(blr, ni, bli * nr));
    dA[2 * p] = a.x; dA[2 * p + 1] = a.y;
    sc[2 * p] = blr * dt; sc[2 * p + 1] = bli * dt;
    float2 pw = a;
    for (int i = 0; i < SEG; ++i) {
        dApow[((size_t)i * P_DIM + p) * 2]     = pw.x;
        dApow[((size_t)i * P_DIM + p) * 2 + 1] = pw.y;
        pw = cmul(pw, a);
    }
}

// ---- k0b: W1T[q][h] (q=2p+c) split bf16; W2T[h][q] = 2*(Cr, -Ci) split bf16 ----
__global__ void k0b(const float* __restrict__ Bre, const float* __restrict__ Bim,
                    const float* __restrict__ Cre, const float* __restrict__ Cim,
                    const float* __restrict__ sc,
                    u16* __restrict__ W1H, u16* __restrict__ W1L,
                    u16* __restrict__ W2H, u16* __restrict__ W2L) {
    int i = blockIdx.x * 256 + threadIdx.x;      // 0..16383
    int p = i >> 7, h = i & 127;
    float2 s = ((const float2*)sc)[p];
    float br = Bre[i], bi = Bim[i];
    float re = fmaf(s.x, br, -s.y * bi);
    float im = fmaf(s.x, bi,  s.y * br);
    u16 hr = f2bf(re); W1H[(2 * p) * H_DIM + h]     = hr; W1L[(2 * p) * H_DIM + h]     = f2bf(re - bf2f(hr));
    u16 hi = f2bf(im); W1H[(2 * p + 1) * H_DIM + h] = hi; W1L[(2 * p + 1) * H_DIM + h] = f2bf(im - bf2f(hi));
    int h2 = i >> 7, p2 = i & 127;
    float cr = 2.f * Cre[i], ci = -2.f * Cim[i];   // CONJ_SYM 2x folded in
    u16 chr = f2bf(cr); W2H[h2 * 256 + 2 * p2]     = chr; W2L[h2 * 256 + 2 * p2]     = f2bf(cr - bf2f(chr));
    u16 chi = f2bf(ci); W2H[h2 * 256 + 2 * p2 + 1] = chi; W2L[h2 * 256 + 2 * p2 + 1] = f2bf(ci - bf2f(chi));
}

// ---- k1: GEMM Bu = X @ W1 (split-bf16 3-pass MFMA), in-LDS seg scan (register-
//      buffered) -> h_loc bf16 out (coalesced) + seg end-states E ----
__global__ __launch_bounds__(256, 3) void k1(const float* __restrict__ x,
                                             const u16* __restrict__ W1H,
                                             const u16* __restrict__ W1L,
                                             const float* __restrict__ dA,
                                             u16* __restrict__ HL,
                                             float* __restrict__ E) {
    __shared__ __align__(16) char smem[32768];
    u16* As_hi = (u16*)smem;              // [64][40] during GEMM
    u16* As_lo = (u16*)(smem + 5120);
    u16* SB    = (u16*)smem;              // [64][256] swizzled, after GEMM
    int t = threadIdx.x, lane = t & 63, wid = t >> 6;   // 4 waves, each 64 rows x 64 cols
    size_t l0 = (size_t)blockIdx.x * ROWS;
    f32x4 acc[4][4];
    #pragma unroll
    for (int a = 0; a < 4; ++a)
        #pragma unroll
        for (int b = 0; b < 4; ++b) acc[a][b] = (f32x4)0.f;
    int ar = lane & 15, ak = (lane >> 4) * 8;

    #pragma unroll
    for (int kt = 0; kt < 4; ++kt) {
        __syncthreads();
        // stage A: 64 rows x 32 k fp32 -> split bf16 (512 float4, 2/thread)
        #pragma unroll
        for (int j = 0; j < 2; ++j) {
            int f = j * 256 + t; int row = f >> 3, c4 = f & 7;
            float4 v = *(const float4*)(x + (l0 + row) * H_DIM + kt * 32 + c4 * 4);
            ushort4 h4, l4;
            h4.x = f2bf(v.x); l4.x = f2bf(v.x - bf2f(h4.x));
            h4.y = f2bf(v.y); l4.y = f2bf(v.y - bf2f(h4.y));
            h4.z = f2bf(v.z); l4.z = f2bf(v.z - bf2f(h4.z));
            h4.w = f2bf(v.w); l4.w = f2bf(v.w - bf2f(h4.w));
            *(ushort4*)&As_hi[row * 40 + c4 * 4] = h4;
            *(ushort4*)&As_lo[row * 40 + c4 * 4] = l4;
        }
        __syncthreads();
        bf16x8 a_hi[4], a_lo[4];
        #pragma unroll
        for (int mf = 0; mf < 4; ++mf) {
            a_hi[mf] = *(const bf16x8*)&As_hi[(mf * 16 + ar) * 40 + ak];
            a_lo[mf] = *(const bf16x8*)&As_lo[(mf * 16 + ar) * 40 + ak];
        }
        #pragma unroll
        for (int nf = 0; nf < 4; ++nf) {
            size_t boff = (size_t)(wid * 64 + nf * 16 + ar) * H_DIM + kt * 32 + ak;
            bf16x8 b_hi = *(const bf16x8*)(W1H + boff);
            bf16x8 b_lo = *(const bf16x8*)(W1L + boff);
            #pragma unroll
            for (int mf = 0; mf < 4; ++mf) {
                acc[mf][nf] = __builtin_amdgcn_mfma_f32_16x16x32_bf16(a_hi[mf], b_hi, acc[mf][nf], 0, 0, 0);
                acc[mf][nf] = __builtin_amdgcn_mfma_f32_16x16x32_bf16(a_lo[mf], b_hi, acc[mf][nf], 0, 0, 0);
                acc[mf][nf] = __builtin_amdgcn_mfma_f32_16x16x32_bf16(a_hi[mf], b_lo, acc[mf][nf], 0, 0, 0);
            }
        }
    }
    __syncthreads();
    // acc -> SB bf16, 16B-block XOR swizzle (blk ^= row&7)
    int sr = (lane >> 4) * 4, scn = lane & 15;
    #pragma unroll
    for (int mf = 0; mf < 4; ++mf)
        #pragma unroll
        for (int nf = 0; nf < 4; ++nf)
            #pragma unroll
            for (int r = 0; r < 4; ++r) {
                int row = mf * 16 + sr + r;
                int col = wid * 64 + nf * 16 + scn;
                SB[row * 256 + (((col >> 3) ^ (row & 7)) << 3) + (col & 7)]
                    = f2bf(acc[mf][nf][r]);
            }
    __syncthreads();
    // seg scan, register-buffered: 2 segs x 128 modes, serial chain in regs only
    {
        int s = t >> 7, p = t & 127;
        float2 a = ((const float2*)dA)[p];
        uint32 buf[SEG];
        #pragma unroll
        for (int i = 0; i < SEG; ++i) {
            int row = s * 32 + i;
            buf[i] = *(const uint32*)&SB[row * 256 + (((p >> 2) ^ (row & 7)) << 3) + (p & 3) * 2];
        }
        float2 h = make_float2(0.f, 0.f);
        #pragma unroll
        for (int i = 0; i < SEG; ++i) {
            h = cfma(a, h, unpk(buf[i]));
            buf[i] = pk(h);
        }
        #pragma unroll
        for (int i = 0; i < SEG; ++i) {
            int row = s * 32 + i;
            *(uint32*)&SB[row * 256 + (((p >> 2) ^ (row & 7)) << 3) + (p & 3) * 2] = buf[i];
        }
        ((float2*)E)[((size_t)blockIdx.x * 2 + s) * P_DIM + p] = h;
    }
    __syncthreads();
    // h_loc store, fully coalesced (un-swizzle read, linear write)
    #pragma unroll
    for (int j = 0; j < 8; ++j) {
        int f = j * 256 + t; int row = f >> 5, blk = f & 31;
        uint4 v = *(const uint4*)&SB[row * 256 + ((blk ^ (row & 7)) << 3)];
        *(uint4*)(HL + (l0 + row) * 256 + blk * 8) = v;
    }
}

// ---- k3: per-mode parallel scan over 4096 seg states -> Hin[seg][p] ----
__global__ __launch_bounds__(256) void k3(const float* __restrict__ E,
                                          const float* __restrict__ dA,
                                          float* __restrict__ Hin) {
    __shared__ float4 s0[256], s1[256];
    int m = blockIdx.x, j = threadIdx.x;
    float2 aS = ((const float2*)dA)[m];
    #pragma unroll
    for (int i = 0; i < 5; ++i) aS = cmul(aS, aS);     // dA^32
    const float2* e = (const float2*)E;
    float2 ebuf[16];
    #pragma unroll
    for (int i = 0; i < 16; ++i) ebuf[i] = e[(size_t)(j * 16 + i) * P_DIM + m];
    float2 B = ebuf[0];
    #pragma unroll
    for (int i = 1; i < 16; ++i) B = cfma(aS, B, ebuf[i]);
    float2 A = aS;
    #pragma unroll
    for (int i = 0; i < 4; ++i) A = cmul(A, A);        // aS^16
    s0[j] = make_float4(A.x, A.y, B.x, B.y);
    __syncthreads();
    float4 *src = s0, *dst = s1;
    for (int d = 1; d < 256; d <<= 1) {
        float4 v = src[j];
        if (j >= d) {
            float4 u = src[j - d];
            float2 uA = make_float2(u.x, u.y), uB = make_float2(u.z, u.w);
            float2 vA = make_float2(v.x, v.y), vB = make_float2(v.z, v.w);
            float2 nA = cmul(uA, vA);
            float2 nB = cfma(vA, uB, vB);
            v = make_float4(nA.x, nA.y, nB.x, nB.y);
        }
        dst[j] = v;
        __syncthreads();
        float4* tmp = src; src = dst; dst = tmp;
    }
    float2 pre = make_float2(0.f, 0.f);
    if (j > 0) { float4 u = src[j - 1]; pre = make_float2(u.z, u.w); }
    float2* hin = (float2*)Hin;
    #pragma unroll
    for (int i = 0; i < 16; ++i) {
        hin[(size_t)(j * 16 + i) * P_DIM + m] = pre;
        pre = cfma(aS, pre, ebuf[i]);
    }
}

// ---- k4: stage h_loc with parallel fixup h = h_loc + dA^{i+1}*Hin, GEMM vs W2,
//      LDS-coalesced y write ----
__global__ __launch_bounds__(256, 4) void k4(const float* __restrict__ x,
                                             const u16* __restrict__ HL,
                                             const u16* __restrict__ W2H,
                                             const u16* __restrict__ W2L,
                                             const float* __restrict__ dApow,
                                             const float* __restrict__ Hin,
                                             const float* __restrict__ Dv,
                                             float* __restrict__ y) {
    __shared__ __align__(16) char smem[33280];
    u16*   SB  = (u16*)smem;       // [64][256] swizzled bf16
    float* SBF = (float*)smem;     // [64][130] f32 y-tile (after GEMM)
    int t = threadIdx.x, lane = t & 63, wid = t >> 6;
    int wr = wid >> 1, wc = wid & 1;                   // wave = 32 rows x 64 cols
    size_t l0 = (size_t)blockIdx.x * ROWS;

    // stage h_loc -> fixup -> LDS swizzled (2048 uint4, 8/thread, all parallel)
    #pragma unroll
    for (int j = 0; j < 8; ++j) {
        int f = j * 256 + t; int row = f >> 5, blk = f & 31;
        uint4 v = *(const uint4*)(HL + (l0 + row) * 256 + blk * 8);
        int m0 = blk * 4;                      // 4 complex modes
        int i = row & 31;                      // position in segment
        int sg = row >> 5;                     // segment within block (0/1)
        const float4* apg = (const float4*)(dApow + ((size_t)i * P_DIM + m0) * 2);
        float4 ap0 = apg[0], ap1 = apg[1];
        const float4* hg = (const float4*)(Hin + (((size_t)blockIdx.x * 2 + sg) * P_DIM + m0) * 2);
        float4 h0 = hg[0], h1 = hg[1];
        float2 c0 = cfma(make_float2(ap0.x, ap0.y), make_float2(h0.x, h0.y), unpk(v.x));
        float2 c1 = cfma(make_float2(ap0.z, ap0.w), make_float2(h0.z, h0.w), unpk(v.y));
        float2 c2 = cfma(make_float2(ap1.x, ap1.y), make_float2(h1.x, h1.y), unpk(v.z));
        float2 c3 = cfma(make_float2(ap1.z, ap1.w), make_float2(h1.z, h1.w), unpk(v.w));
        uint4 o; o.x = pk(c0); o.y = pk(c1); o.z = pk(c2); o.w = pk(c3);
        *(uint4*)&SB[row * 256 + ((blk ^ (row & 7)) << 3)] = o;
    }
    __syncthreads();

    // GEMM: y(64x128) = h(64x256) @ W2T^T, split-bf16 2-pass
    f32x4 acc[2][4];
    #pragma unroll
    for (int a = 0; a < 2; ++a)
        #pragma unroll
        for (int b = 0; b < 4; ++b) acc[a][b] = (f32x4)0.f;
    int ar = lane & 15, akb = lane >> 4;
    #pragma unroll
    for (int kk = 0; kk < 8; ++kk) {
        bf16x8 af[2];
        #pragma unroll
        for (int mf = 0; mf < 2; ++mf) {
            int row = wr * 32 + mf * 16 + ar;
            int blk = kk * 4 + akb;
            af[mf] = *(const bf16x8*)&SB[row * 256 + ((blk ^ (row & 7)) << 3)];
        }
        #pragma unroll
        for (int nf = 0; nf < 4; ++nf) {
            size_t boff = (size_t)(wc * 64 + nf * 16 + ar) * 256 + kk * 32 + akb * 8;
            bf16x8 b_hi = *(const bf16x8*)(W2H + boff);
            bf16x8 b_lo = *(const bf16x8*)(W2L + boff);
            #pragma unroll
            for (int mf = 0; mf < 2; ++mf) {
                acc[mf][nf] = __builtin_amdgcn_mfma_f32_16x16x32_bf16(af[mf], b_hi, acc[mf][nf], 0, 0, 0);
                acc[mf][nf] = __builtin_amdgcn_mfma_f32_16x16x32_bf16(af[mf], b_lo, acc[mf][nf], 0, 0, 0);
            }
        }
    }
    __syncthreads();
    // acc -> SBF[64][130] (pad 130: conflict-free row groups)
    int sr = (lane >> 4) * 4, scn = lane & 15;
    #pragma unroll
    for (int mf = 0; mf < 2; ++mf)
        #pragma unroll
        for (int nf = 0; nf < 4; ++nf)
            #pragma unroll
            for (int r = 0; r < 4; ++r) {
                int row = wr * 32 + mf * 16 + sr + r;
                int col = wc * 64 + nf * 16 + scn;
                SBF[row * 130 + col] = acc[mf][nf][r];
            }
    __syncthreads();
    // y write: fully coalesced float4 rows, fused x*D (2x already in W2)
    int c4 = t & 31;
    float4 dv = *(const float4*)(Dv + c4 * 4);
    #pragma unroll
    for (int j = 0; j < 8; ++j) {
        int row = j * 8 + (t >> 5);
        float4 sv = *(float4*)&SBF[row * 130 + c4 * 4];
        float4 xv = *(const float4*)(x + (l0 + row) * H_DIM + c4 * 4);
        float4 out;
        out.x = fmaf(xv.x, dv.x, sv.x);
        out.y = fmaf(xv.y, dv.y, sv.y);
        out.z = fmaf(xv.z, dv.z, sv.z);
        out.w = fmaf(xv.w, dv.w, sv.w);
        *(float4*)(y + (l0 + row) * H_DIM + c4 * 4) = out;
    }
}

extern "C" void kernel_launch(void* const* d_in, const int* in_sizes, int n_in,
                              void* d_out, int out_size, void* d_ws, size_t ws_size,
                              hipStream_t stream) {
    const float* x     = (const float*)d_in[0];
    const float* Arl   = (const float*)d_in[1];
    const float* Ai    = (const float*)d_in[2];
    const float* Bre   = (const float*)d_in[3];
    const float* Bim   = (const float*)d_in[4];
    const float* Cre   = (const float*)d_in[5];
    const float* Cim   = (const float*)d_in[6];
    const float* Dv    = (const float*)d_in[7];
    const float* invdt = (const float*)d_in[8];
    float* y  = (float*)d_out;
    float* ws = (float*)d_ws;

    u16* hl  = (u16*)(ws + OFF_HL);
    u16* w1h = (u16*)(ws + OFF_W1H);
    u16* w1l = (u16*)(ws + OFF_W1L);
    u16* w2h = (u16*)(ws + OFF_W2H);
    u16* w2l = (u16*)(ws + OFF_W2L);

    k0a<<<1, 128, 0, stream>>>(Arl, Ai, invdt, ws + OFF_DA, ws + OFF_SC, ws + OFF_POW);
    k0b<<<64, 256, 0, stream>>>(Bre, Bim, Cre, Cim, ws + OFF_SC, w1h, w1l, w2h, w2l);
    k1<<<NBLK, 256, 0, stream>>>(x, w1h, w1l, ws + OFF_DA, hl, ws + OFF_E);
    k3<<<128, 256, 0, stream>>>(ws + OFF_E, ws + OFF_DA, ws + OFF_HIN);
    k4<<<NBLK, 256, 0, stream>>>(x, hl, w2h, w2l, ws + OFF_POW,
                                 ws + OFF_HIN, Dv, y);
}